// Round 9
// baseline (80.676 us; speedup 1.0000x reference)
//
#include <hip/hip_runtime.h>
#include <stdint.h>

// Problem constants (match reference)
#define BB 8
#define SS 4096
#define TOKEN_BITS 12
#define EMB 1024
#define NB 12
#define TABLE 4096
#define POS_BITS 13
#define SPB 8   // sequence positions per block in ram_embed

typedef float f32x4 __attribute__((ext_vector_type(4)));

// ---------------------------------------------------------------------------
// Kernel 1 (R3 verbatim): build remapT[n][pat-bits] — pattern-packed remap.
// ---------------------------------------------------------------------------
__global__ __launch_bounds__(256) void build_remapT(const float* __restrict__ tables,
                                                    const int* __restrict__ conn,
                                                    uint64_t* __restrict__ remapT) {
    __shared__ float row[TABLE];
    __shared__ int csh[NB];
    const int n = blockIdx.x;
    const int t = threadIdx.x;
    if (t < NB) csh[t] = conn[n * NB + t];
    const f32x4* src = (const f32x4*)(tables + (size_t)n * TABLE);
    f32x4* dst = (f32x4*)row;
#pragma unroll
    for (int i = 0; i < 4; ++i)
        dst[t + 256 * i] = src[t + 256 * i];
    __syncthreads();
    int cr[NB];
#pragma unroll
    for (int j = 0; j < NB; ++j) cr[j] = csh[j];
    for (int base = 0; base < TABLE; base += 256) {
        int pat = base + t;
        int addr = 0;
#pragma unroll
        for (int j = 0; j < NB; ++j)
            addr = (addr << 1) | ((pat >> cr[j]) & 1);   // j=0 is MSB (reference order)
        uint64_t m = __ballot(row[addr] != 0.0f);
        if ((t & 63) == 0)
            remapT[(size_t)n * (TABLE / 64) + (pat >> 6)] = m;
    }
}

// ---------------------------------------------------------------------------
// Kernel 2 (R3 verbatim): bit-transpose remapT -> remap[pat][neuron-bits].
// ---------------------------------------------------------------------------
__global__ __launch_bounds__(256) void transpose_remap(const uint32_t* __restrict__ remapT32,
                                                       uint32_t* __restrict__ remap32) {
    const int w   = blockIdx.x >> 4;                       // 0..31
    const int pat = ((blockIdx.x & 15) << 8) | threadIdx.x;
    const int wordIdx = pat >> 5;
    const int bit     = pat & 31;
    uint32_t res = 0;
#pragma unroll
    for (int i = 0; i < 32; ++i) {
        int n = 32 * w + i;
        res |= ((remapT32[(size_t)n * (TABLE / 32) + wordIdx] >> bit) & 1u) << i;
    }
    remap32[(size_t)pat * (EMB / 32) + w] = res;
}

// ---------------------------------------------------------------------------
// Kernel 3 (R3/R5 verbatim): main embedding, SPB=8, plain f32x4 stores.
// ---------------------------------------------------------------------------
__global__ __launch_bounds__(256) void ram_embed(const int* __restrict__ tokens,
                                                 const uint32_t* __restrict__ remap,
                                                 float* __restrict__ out) {
    const int g0 = blockIdx.x * SPB;            // first b*S+s row index
    const int t  = threadIdx.x;
    __shared__ int tok[SPB * TOKEN_BITS];
    __shared__ int pats[SPB];
    if (t < SPB * TOKEN_BITS)
        tok[t] = tokens[(size_t)g0 * TOKEN_BITS + t];
    __syncthreads();
    if (t < SPB) {
        int p = 0;
#pragma unroll
        for (int j = 0; j < TOKEN_BITS; ++j)
            p |= (tok[t * TOKEN_BITS + j] & 1) << j;
        pats[t] = p;
    }
    __syncthreads();

    const int n0 = t * 4;
    int sh[4];
#pragma unroll
    for (int u = 0; u < 4; ++u)
        sh[u] = POS_BITS - 1 - ((n0 + u) % POS_BITS);
    const int sbase = g0 & (SS - 1);            // SPB divides SS, so b is fixed

    for (int k = 0; k < SPB; ++k) {
        const int pat = pats[k];
        const int s   = sbase + k;
        uint32_t word = remap[(size_t)pat * (EMB / 32) + (t >> 3)];
        uint32_t nib  = (word >> ((t & 7) * 4)) & 0xFu;
        uint32_t pn   =  (uint32_t)((s >> sh[0]) & 1)
                      | ((uint32_t)((s >> sh[1]) & 1) << 1)
                      | ((uint32_t)((s >> sh[2]) & 1) << 2)
                      | ((uint32_t)((s >> sh[3]) & 1) << 3);
        uint32_t x = nib ^ pn;
        f32x4 o;
        o.x = (x & 1u) ? 1.0f : 0.0f;
        o.y = (x & 2u) ? 1.0f : 0.0f;
        o.z = (x & 4u) ? 1.0f : 0.0f;
        o.w = (x & 8u) ? 1.0f : 0.0f;
        *(f32x4*)(out + (size_t)(g0 + k) * EMB + n0) = o;
    }
}

// ---------------------------------------------------------------------------
extern "C" void kernel_launch(void* const* d_in, const int* in_sizes, int n_in,
                              void* d_out, int out_size, void* d_ws, size_t ws_size,
                              hipStream_t stream) {
    const int*   tokens = (const int*)d_in[0];
    const float* tables = (const float*)d_in[1];
    const int*   conn   = (const int*)d_in[2];
    float*       out    = (float*)d_out;

    // ws layout: [0, 512KB) remapT (pattern-packed), [512KB, 1MB) remap (neuron-packed)
    uint64_t* remapT = (uint64_t*)d_ws;
    uint32_t* remap  = (uint32_t*)(remapT + EMB * (TABLE / 64));

    // INSTRUMENTATION: build and transpose launched 5x each (idempotent —
    // identical ws contents every time). (dur - 39.15us) / 4 = t_build + t_transpose.
    for (int r = 0; r < 5; ++r) {
        build_remapT<<<EMB, 256, 0, stream>>>(tables, conn, remapT);
        transpose_remap<<<(TABLE / 256) * (EMB / 32), 256, 0, stream>>>(
            (const uint32_t*)remapT, remap);
    }
    ram_embed<<<BB * SS / SPB, 256, 0, stream>>>(tokens, remap, out);
}

// Round 10
// 36.493 us; speedup vs baseline: 2.2107x; 2.2107x over previous
//
#include <hip/hip_runtime.h>
#include <stdint.h>

// Problem constants (match reference)
#define BB 8
#define SS 4096
#define TOKEN_BITS 12
#define EMB 1024
#define NB 12
#define TABLE 4096
#define POS_BITS 13
#define SPB 8   // sequence positions per block in ram_embed

typedef float f32x4 __attribute__((ext_vector_type(4)));

// ---------------------------------------------------------------------------
// Kernel 1: build remapT[n][pat-bits] — pattern-packed remap.
// One block per neuron; stage the 16 KB row in LDS (the only pass over the
// 16 MB table). Address math uses the XOR-mask decomposition verified in R6:
//   pat = t + 256*m  =>  addr(pat) = addr_low(t) ^ h0[m&1] ^ h1[m&2] ...
// addr_low: contributions of conn bits < 8 (depend only on lane t), computed
// once (~48 VALU). Per-pattern: <=4 compile-time XORs + LDS read + ballot,
// vs ~38 VALU for the serial 12-step chain — build was VALU-bound (R9 split).
// ---------------------------------------------------------------------------
__global__ __launch_bounds__(256) void build_remapT(const float* __restrict__ tables,
                                                    const int* __restrict__ conn,
                                                    uint64_t* __restrict__ remapT) {
    __shared__ float row[TABLE];
    const int n = blockIdx.x;
    const int t = threadIdx.x;

    const f32x4* src = (const f32x4*)(tables + (size_t)n * TABLE);
    f32x4* dst = (f32x4*)row;
#pragma unroll
    for (int i = 0; i < 4; ++i)
        dst[t + 256 * i] = src[t + 256 * i];

    // address decomposition (overlaps staging latency); conn reads are
    // block-uniform -> scalar loads
    uint32_t al = 0, h0 = 0, h1 = 0, h2 = 0, h3 = 0;
#pragma unroll
    for (int j = 0; j < NB; ++j) {
        const int c = conn[n * NB + j];
        const uint32_t bp = 1u << (NB - 1 - j);       // j=0 is MSB (reference order)
        if (c < 8)        al |= ((t >> c) & 1) ? bp : 0u;
        else if (c == 8)  h0 |= bp;
        else if (c == 9)  h1 |= bp;
        else if (c == 10) h2 |= bp;
        else              h3 |= bp;
    }
    __syncthreads();

#pragma unroll
    for (int m = 0; m < 16; ++m) {
        uint32_t addr = al;
        if (m & 1) addr ^= h0;
        if (m & 2) addr ^= h1;
        if (m & 4) addr ^= h2;
        if (m & 8) addr ^= h3;
        const uint64_t mask = __ballot(row[addr] != 0.0f);
        if ((t & 63) == 0)
            remapT[(size_t)n * (TABLE / 64) + (t >> 6) + 4 * m] = mask;
    }
}

// ---------------------------------------------------------------------------
// Kernel 2 (R3 verbatim): bit-transpose remapT -> remap[pat][neuron-bits].
// ---------------------------------------------------------------------------
__global__ __launch_bounds__(256) void transpose_remap(const uint32_t* __restrict__ remapT32,
                                                       uint32_t* __restrict__ remap32) {
    const int w   = blockIdx.x >> 4;                       // 0..31
    const int pat = ((blockIdx.x & 15) << 8) | threadIdx.x;
    const int wordIdx = pat >> 5;
    const int bit     = pat & 31;
    uint32_t res = 0;
#pragma unroll
    for (int i = 0; i < 32; ++i) {
        int n = 32 * w + i;
        res |= ((remapT32[(size_t)n * (TABLE / 32) + wordIdx] >> bit) & 1u) << i;
    }
    remap32[(size_t)pat * (EMB / 32) + w] = res;
}

// ---------------------------------------------------------------------------
// Kernel 3 (R3/R5 verbatim): main embedding, SPB=8, plain f32x4 stores.
// Measured at 22.1 us = 6.1 TB/s (R8 split) — at the write roofline.
// ---------------------------------------------------------------------------
__global__ __launch_bounds__(256) void ram_embed(const int* __restrict__ tokens,
                                                 const uint32_t* __restrict__ remap,
                                                 float* __restrict__ out) {
    const int g0 = blockIdx.x * SPB;            // first b*S+s row index
    const int t  = threadIdx.x;
    __shared__ int tok[SPB * TOKEN_BITS];
    __shared__ int pats[SPB];
    if (t < SPB * TOKEN_BITS)
        tok[t] = tokens[(size_t)g0 * TOKEN_BITS + t];
    __syncthreads();
    if (t < SPB) {
        int p = 0;
#pragma unroll
        for (int j = 0; j < TOKEN_BITS; ++j)
            p |= (tok[t * TOKEN_BITS + j] & 1) << j;
        pats[t] = p;
    }
    __syncthreads();

    const int n0 = t * 4;
    int sh[4];
#pragma unroll
    for (int u = 0; u < 4; ++u)
        sh[u] = POS_BITS - 1 - ((n0 + u) % POS_BITS);
    const int sbase = g0 & (SS - 1);            // SPB divides SS, so b is fixed

    for (int k = 0; k < SPB; ++k) {
        const int pat = pats[k];
        const int s   = sbase + k;
        uint32_t word = remap[(size_t)pat * (EMB / 32) + (t >> 3)];
        uint32_t nib  = (word >> ((t & 7) * 4)) & 0xFu;
        uint32_t pn   =  (uint32_t)((s >> sh[0]) & 1)
                      | ((uint32_t)((s >> sh[1]) & 1) << 1)
                      | ((uint32_t)((s >> sh[2]) & 1) << 2)
                      | ((uint32_t)((s >> sh[3]) & 1) << 3);
        uint32_t x = nib ^ pn;
        f32x4 o;
        o.x = (x & 1u) ? 1.0f : 0.0f;
        o.y = (x & 2u) ? 1.0f : 0.0f;
        o.z = (x & 4u) ? 1.0f : 0.0f;
        o.w = (x & 8u) ? 1.0f : 0.0f;
        *(f32x4*)(out + (size_t)(g0 + k) * EMB + n0) = o;
    }
}

// ---------------------------------------------------------------------------
extern "C" void kernel_launch(void* const* d_in, const int* in_sizes, int n_in,
                              void* d_out, int out_size, void* d_ws, size_t ws_size,
                              hipStream_t stream) {
    const int*   tokens = (const int*)d_in[0];
    const float* tables = (const float*)d_in[1];
    const int*   conn   = (const int*)d_in[2];
    float*       out    = (float*)d_out;

    // ws layout: [0, 512KB) remapT (pattern-packed), [512KB, 1MB) remap (neuron-packed)
    uint64_t* remapT = (uint64_t*)d_ws;
    uint32_t* remap  = (uint32_t*)(remapT + EMB * (TABLE / 64));

    build_remapT<<<EMB, 256, 0, stream>>>(tables, conn, remapT);
    transpose_remap<<<(TABLE / 256) * (EMB / 32), 256, 0, stream>>>(
        (const uint32_t*)remapT, remap);
    ram_embed<<<BB * SS / SPB, 256, 0, stream>>>(tokens, remap, out);
}

// Round 11
// 36.194 us; speedup vs baseline: 2.2290x; 1.0083x over previous
//
#include <hip/hip_runtime.h>
#include <stdint.h>

// Problem constants (match reference)
#define BB 8
#define SS 4096
#define TOKEN_BITS 12
#define EMB 1024
#define NB 12
#define TABLE 4096
#define POS_BITS 13
#define SPB 8   // sequence positions per block in ram_embed

typedef float f32x4 __attribute__((ext_vector_type(4)));

#define GLOBAL_AS(p) ((const __attribute__((address_space(1))) void*)(p))
#define LDS_AS(p)    ((__attribute__((address_space(3))) void*)(p))

// ---------------------------------------------------------------------------
// Kernel 1: build remapT[n][pat-bits] (pattern-packed). One block per neuron.
// Staging now via global_load_lds width=16 (async direct-to-LDS; layout is
// linear = wave-uniform base + lane*16, the required pattern). Address math
// is the R10 XOR-mask decomposition (verified): per-pattern <=4 XORs.
// ---------------------------------------------------------------------------
__global__ __launch_bounds__(256) void build_remapT(const float* __restrict__ tables,
                                                    const int* __restrict__ conn,
                                                    uint64_t* __restrict__ remapT) {
    __shared__ float row[TABLE];                // 16 KB
    const int n = blockIdx.x;
    const int t = threadIdx.x;

    const float* src = tables + (size_t)n * TABLE;
#pragma unroll
    for (int i = 0; i < 4; ++i) {
        const int e = (t + 256 * i) * 4;        // element offset (16 B per lane)
        __builtin_amdgcn_global_load_lds(GLOBAL_AS(src + e), LDS_AS(row + e), 16, 0, 0);
    }

    // address decomposition (overlaps staging); conn loads are block-uniform
    uint32_t al = 0, h0 = 0, h1 = 0, h2 = 0, h3 = 0;
#pragma unroll
    for (int j = 0; j < NB; ++j) {
        const int c = conn[n * NB + j];
        const uint32_t bp = 1u << (NB - 1 - j);       // j=0 is MSB (reference order)
        if (c < 8)        al |= ((t >> c) & 1) ? bp : 0u;
        else if (c == 8)  h0 |= bp;
        else if (c == 9)  h1 |= bp;
        else if (c == 10) h2 |= bp;
        else              h3 |= bp;
    }
    __syncthreads();                             // drains vmcnt incl. lds-DMA

#pragma unroll
    for (int m = 0; m < 16; ++m) {
        uint32_t addr = al;
        if (m & 1) addr ^= h0;
        if (m & 2) addr ^= h1;
        if (m & 4) addr ^= h2;
        if (m & 8) addr ^= h3;
        const uint64_t mask = __ballot(row[addr] != 0.0f);
        if ((t & 63) == 0)
            remapT[(size_t)n * (TABLE / 64) + (t >> 6) + 4 * m] = mask;
    }
}

// ---------------------------------------------------------------------------
// Kernel 2: ballot-transpose remapT -> remap[pat][neuron-bits].
// Wave layout: lanes = 64 consecutive neurons, each lane loads ONE word
// (32 patterns) of its neuron's remapT row. 32 ballots then produce the
// 64-neuron-packed doubleword for each pattern; lane k keeps lo(ballot_k),
// lane 32+k keeps hi(ballot_k); one 4 B store per lane. 32x fewer L2 loads
// than the per-thread gather transpose. Block's 4 waves share pw lines (L1).
// ---------------------------------------------------------------------------
__global__ __launch_bounds__(256) void transpose_ballot(const uint32_t* __restrict__ remapT32,
                                                        uint32_t* __restrict__ remap32) {
    const int t    = threadIdx.x;
    const int lane = t & 63;
    const int wv   = t >> 6;                        // 0..3
    const int nb   = (blockIdx.x >> 5) * 64;        // neuron base (16 groups)
    const int pw   = (blockIdx.x & 31) * 4 + wv;    // pattern word 0..127

    const uint32_t v = remapT32[(size_t)(nb + lane) * (TABLE / 32) + pw];
    uint32_t keep = 0;
#pragma unroll
    for (int b = 0; b < 32; ++b) {
        const uint64_t m = __ballot(((v >> b) & 1u) != 0u);
        const uint32_t half = (lane < 32) ? (uint32_t)m : (uint32_t)(m >> 32);
        if ((lane & 31) == b) keep = half;
    }
    const int pat = pw * 32 + (lane & 31);
    const int w   = (nb >> 5) + (lane >> 5);
    remap32[(size_t)pat * (EMB / 32) + w] = keep;
}

// ---------------------------------------------------------------------------
// Kernel 3 (R3/R5 verbatim): main embedding, SPB=8, plain f32x4 stores.
// Measured at 22.1 us = 6.1 TB/s (R8 split) — at the write roofline.
// ---------------------------------------------------------------------------
__global__ __launch_bounds__(256) void ram_embed(const int* __restrict__ tokens,
                                                 const uint32_t* __restrict__ remap,
                                                 float* __restrict__ out) {
    const int g0 = blockIdx.x * SPB;            // first b*S+s row index
    const int t  = threadIdx.x;
    __shared__ int tok[SPB * TOKEN_BITS];
    __shared__ int pats[SPB];
    if (t < SPB * TOKEN_BITS)
        tok[t] = tokens[(size_t)g0 * TOKEN_BITS + t];
    __syncthreads();
    if (t < SPB) {
        int p = 0;
#pragma unroll
        for (int j = 0; j < TOKEN_BITS; ++j)
            p |= (tok[t * TOKEN_BITS + j] & 1) << j;
        pats[t] = p;
    }
    __syncthreads();

    const int n0 = t * 4;
    int sh[4];
#pragma unroll
    for (int u = 0; u < 4; ++u)
        sh[u] = POS_BITS - 1 - ((n0 + u) % POS_BITS);
    const int sbase = g0 & (SS - 1);            // SPB divides SS, so b is fixed

    for (int k = 0; k < SPB; ++k) {
        const int pat = pats[k];
        const int s   = sbase + k;
        uint32_t word = remap[(size_t)pat * (EMB / 32) + (t >> 3)];
        uint32_t nib  = (word >> ((t & 7) * 4)) & 0xFu;
        uint32_t pn   =  (uint32_t)((s >> sh[0]) & 1)
                      | ((uint32_t)((s >> sh[1]) & 1) << 1)
                      | ((uint32_t)((s >> sh[2]) & 1) << 2)
                      | ((uint32_t)((s >> sh[3]) & 1) << 3);
        uint32_t x = nib ^ pn;
        f32x4 o;
        o.x = (x & 1u) ? 1.0f : 0.0f;
        o.y = (x & 2u) ? 1.0f : 0.0f;
        o.z = (x & 4u) ? 1.0f : 0.0f;
        o.w = (x & 8u) ? 1.0f : 0.0f;
        *(f32x4*)(out + (size_t)(g0 + k) * EMB + n0) = o;
    }
}

// ---------------------------------------------------------------------------
extern "C" void kernel_launch(void* const* d_in, const int* in_sizes, int n_in,
                              void* d_out, int out_size, void* d_ws, size_t ws_size,
                              hipStream_t stream) {
    const int*   tokens = (const int*)d_in[0];
    const float* tables = (const float*)d_in[1];
    const int*   conn   = (const int*)d_in[2];
    float*       out    = (float*)d_out;

    // ws layout: [0, 512KB) remapT (pattern-packed), [512KB, 1MB) remap (neuron-packed)
    uint64_t* remapT = (uint64_t*)d_ws;
    uint32_t* remap  = (uint32_t*)(remapT + EMB * (TABLE / 64));

    build_remapT<<<EMB, 256, 0, stream>>>(tables, conn, remapT);
    transpose_ballot<<<512, 256, 0, stream>>>((const uint32_t*)remapT, remap);
    ram_embed<<<BB * SS / SPB, 256, 0, stream>>>(tokens, remap, out);
}